// Round 3
// baseline (2494.274 us; speedup 1.0000x reference)
//
#include <hip/hip_runtime.h>
#include <stdint.h>

// Problem constants (from reference)
#define N_USER 100000
#define N_ITEM 200000
#define N_NODE 300000   // N_USER + N_ITEM
#define DIM    64
#define N_EDGE 10000000
#define N_LAYER 3

#define BROWS 128                              // rows per bucket (row >> 7)
#define NB ((N_NODE + BROWS - 1) / BROWS)      // 2344 buckets

// ---------------------------------------------------------------------------
// concat(u, i) -> cur  and  acc (= layer-0 term of the output sum)
// ---------------------------------------------------------------------------
__global__ __launch_bounds__(256) void concat_init(
    const float* __restrict__ uE, const float* __restrict__ iE,
    float* __restrict__ cur, float* __restrict__ acc)
{
    int i = blockIdx.x * blockDim.x + threadIdx.x;    // float4 index
    const int n4 = N_NODE * DIM / 4;
    if (i >= n4) return;
    int off = i * 4;
    const int ubound = N_USER * DIM;
    const float* src = (off < ubound) ? (uE + off) : (iE + (off - ubound));
    float4 x = *(const float4*)src;
    *(float4*)(cur + off) = x;
    *(float4*)(acc + off) = x;
}

// ---------------------------------------------------------------------------
// Build step 1: bucket-level histogram with LDS privatization.
// 2344 bins x 4B = 9.4 KB LDS. Removes 10M global atomics from the old hist.
// ---------------------------------------------------------------------------
__global__ __launch_bounds__(256) void hist_buckets(
    const int* __restrict__ rows, int* __restrict__ bucketCnt)
{
    __shared__ int h[NB];
    for (int i = threadIdx.x; i < NB; i += 256) h[i] = 0;
    __syncthreads();
    const int n4 = N_EDGE / 4;
    const int stride = gridDim.x * blockDim.x;
    for (int i = blockIdx.x * blockDim.x + threadIdx.x; i < n4; i += stride) {
        int4 r = ((const int4*)rows)[i];
        atomicAdd(&h[r.x >> 7], 1);
        atomicAdd(&h[r.y >> 7], 1);
        atomicAdd(&h[r.z >> 7], 1);
        atomicAdd(&h[r.w >> 7], 1);
    }
    __syncthreads();
    for (int i = threadIdx.x; i < NB; i += 256) {
        int v = h[i];
        if (v) atomicAdd(&bucketCnt[i], v);
    }
}

// ---------------------------------------------------------------------------
// Build step 2: exclusive scan over 2344 bucket counts (single block).
// ---------------------------------------------------------------------------
__global__ __launch_bounds__(256) void bucket_scan(
    const int* __restrict__ cnt, int* __restrict__ bptr,
    int* __restrict__ cursorB)
{
    __shared__ int s[256];
    int carry = 0;
    for (int base = 0; base < NB; base += 256) {
        int i = base + threadIdx.x;
        int x = (i < NB) ? cnt[i] : 0;
        s[threadIdx.x] = x;
        __syncthreads();
        for (int off = 1; off < 256; off <<= 1) {
            int t = (threadIdx.x >= off) ? s[threadIdx.x - off] : 0;
            __syncthreads();
            s[threadIdx.x] += t;
            __syncthreads();
        }
        int incl  = s[threadIdx.x];
        int total = s[255];
        if (i < NB) { int v = incl - x + carry; bptr[i] = v; cursorB[i] = v; }
        carry += total;
        __syncthreads();
    }
    if (threadIdx.x == 0) bptr[NB] = N_EDGE;
}

// ---------------------------------------------------------------------------
// Build step 3 (pass A): scatter edges into bucket-grouped tmp array.
// Appends to 2344 bucket tails -> near-sequential writes, L2 line-assembly.
// ---------------------------------------------------------------------------
__global__ __launch_bounds__(256) void bucket_scatter(
    const int* __restrict__ rows, const int* __restrict__ cols,
    const float* __restrict__ vals, int* __restrict__ cursorB,
    int2* __restrict__ tmp, unsigned char* __restrict__ rowlow)
{
    int i = blockIdx.x * blockDim.x + threadIdx.x;   // group of 4 edges
    const int n4 = N_EDGE / 4;
    if (i >= n4) return;
    int4   r = ((const int4*)rows)[i];
    int4   c = ((const int4*)cols)[i];
    float4 v = ((const float4*)vals)[i];

    int pos = atomicAdd(&cursorB[r.x >> 7], 1);
    tmp[pos] = make_int2(c.x, __float_as_int(v.x));
    rowlow[pos] = (unsigned char)(r.x & (BROWS - 1));

    pos = atomicAdd(&cursorB[r.y >> 7], 1);
    tmp[pos] = make_int2(c.y, __float_as_int(v.y));
    rowlow[pos] = (unsigned char)(r.y & (BROWS - 1));

    pos = atomicAdd(&cursorB[r.z >> 7], 1);
    tmp[pos] = make_int2(c.z, __float_as_int(v.z));
    rowlow[pos] = (unsigned char)(r.z & (BROWS - 1));

    pos = atomicAdd(&cursorB[r.w >> 7], 1);
    tmp[pos] = make_int2(c.w, __float_as_int(v.w));
    rowlow[pos] = (unsigned char)(r.w & (BROWS - 1));
}

// ---------------------------------------------------------------------------
// Build step 4 (pass B): per-bucket counting sort -> final CSR pairs + rowPtr.
// One block per bucket. LDS row-hist (128 bins) + LDS scan + LDS cursors.
// All global writes confined to the bucket's contiguous window.
// ---------------------------------------------------------------------------
__global__ __launch_bounds__(256) void build_csr_bucket(
    const int* __restrict__ bptr, const int2* __restrict__ tmp,
    const unsigned char* __restrict__ rowlow,
    int* __restrict__ rowPtr, int2* __restrict__ pairs)
{
    __shared__ int h[BROWS];
    __shared__ int sc[BROWS];
    const int b   = blockIdx.x;
    const int bs  = bptr[b];
    const int be  = bptr[b + 1];
    const int n   = be - bs;
    const int tid = threadIdx.x;

    if (tid < BROWS) h[tid] = 0;
    __syncthreads();
    for (int i = tid; i < n; i += 256)
        atomicAdd(&h[rowlow[bs + i]], 1);
    __syncthreads();
    if (tid < BROWS) sc[tid] = h[tid];
    __syncthreads();
    for (int off = 1; off < BROWS; off <<= 1) {
        int t = (tid >= off && tid < BROWS) ? sc[tid - off] : 0;
        __syncthreads();
        if (tid < BROWS) sc[tid] += t;
        __syncthreads();
    }
    if (tid < BROWS) {
        int excl = sc[tid] - h[tid];
        int row  = b * BROWS + tid;
        if (row < N_NODE) rowPtr[row] = bs + excl;
        h[tid] = excl;                 // reuse as local cursor
    }
    if (b == NB - 1 && tid == 0) rowPtr[N_NODE] = be;   // be == N_EDGE
    __syncthreads();
    for (int i = tid; i < n; i += 256) {
        int r = rowlow[bs + i];
        int p = bs + atomicAdd(&h[r], 1);
        pairs[p] = tmp[bs + i];
    }
}

// ---------------------------------------------------------------------------
// CSR SpMM, no atomics. One wave per row; lane = dim element. acc += fused.
// ---------------------------------------------------------------------------
__global__ __launch_bounds__(256) void spmm_csr(
    const int*  __restrict__ rowPtr,
    const int2* __restrict__ pairs,
    const float* __restrict__ cur,
    float* __restrict__ nxt,
    float* __restrict__ acc)
{
    const int wid  = (blockIdx.x * blockDim.x + threadIdx.x) >> 6;  // row
    const int lane = threadIdx.x & 63;
    if (wid >= N_NODE) return;

    const int start = rowPtr[wid];
    const int end   = rowPtr[wid + 1];

    float sum = 0.0f;
    for (int e0 = start; e0 < end; e0 += 64) {
        const int n = min(64, end - e0);
        int   c = 0;
        float v = 0.0f;
        if (lane < n) {
            int2 p = pairs[e0 + lane];
            c = p.x;
            v = __int_as_float(p.y);
        }
        int j = 0;
        for (; j + 4 <= n; j += 4) {
            int   c0 = __shfl(c, j);     float v0 = __shfl(v, j);
            int   c1 = __shfl(c, j + 1); float v1 = __shfl(v, j + 1);
            int   c2 = __shfl(c, j + 2); float v2 = __shfl(v, j + 2);
            int   c3 = __shfl(c, j + 3); float v3 = __shfl(v, j + 3);
            float x0 = cur[c0 * DIM + lane];
            float x1 = cur[c1 * DIM + lane];
            float x2 = cur[c2 * DIM + lane];
            float x3 = cur[c3 * DIM + lane];
            sum += v0 * x0;
            sum += v1 * x1;
            sum += v2 * x2;
            sum += v3 * x3;
        }
        for (; j < n; ++j) {
            int   cc = __shfl(c, j);
            float vv = __shfl(v, j);
            sum += vv * cur[cc * DIM + lane];
        }
    }
    const int idx = wid * DIM + lane;
    nxt[idx] = sum;
    acc[idx] += sum;
}

// ---------------------------------------------------------------------------
// Fallback path (atomic scatter) if ws_size is too small for CSR buffers
// ---------------------------------------------------------------------------
__global__ __launch_bounds__(256) void spmm_atomic(
    const int*   __restrict__ rows,
    const int*   __restrict__ cols,
    const float* __restrict__ vals,
    const float* __restrict__ cur,
    float*       __restrict__ next)
{
    const int lane = threadIdx.x & 63;
    const int wave = (blockIdx.x * blockDim.x + threadIdx.x) >> 6;
    const int base = wave * 64;
    if (base >= N_EDGE) return;

    int   r64 = 0, c64 = 0;
    float v64 = 0.0f;
    const int e = base + lane;
    if (e < N_EDGE) { r64 = rows[e]; c64 = cols[e]; v64 = vals[e]; }
    const int nloc = min(64, N_EDGE - base);
    const int sub = lane >> 4;
    const int d4  = (lane & 15) << 2;

    #pragma unroll 4
    for (int j = 0; j < 64; j += 4) {
        const int   eidx = j + sub;
        const int   r = __shfl(r64, eidx);
        const int   c = __shfl(c64, eidx);
        const float v = __shfl(v64, eidx);
        if (eidx < nloc) {
            const float4 x = *(const float4*)(cur + c * DIM + d4);
            float* dst = next + r * DIM + d4;
            unsafeAtomicAdd(dst + 0, v * x.x);
            unsafeAtomicAdd(dst + 1, v * x.y);
            unsafeAtomicAdd(dst + 2, v * x.z);
            unsafeAtomicAdd(dst + 3, v * x.w);
        }
    }
}

__global__ __launch_bounds__(256) void acc_add(
    const float* __restrict__ next, float* __restrict__ acc)
{
    int i = blockIdx.x * blockDim.x + threadIdx.x;
    const int n4 = N_NODE * DIM / 4;
    if (i >= n4) return;
    int off = i * 4;
    float4 a = *(float4*)(acc + off);
    float4 b = *(const float4*)(next + off);
    a.x += b.x; a.y += b.y; a.z += b.z; a.w += b.w;
    *(float4*)(acc + off) = a;
}

extern "C" void kernel_launch(void* const* d_in, const int* in_sizes, int n_in,
                              void* d_out, int out_size, void* d_ws, size_t ws_size,
                              hipStream_t stream)
{
    const int*   rows = (const int*)  d_in[0];
    const int*   cols = (const int*)  d_in[1];
    const float* vals = (const float*)d_in[2];
    const float* uE   = (const float*)d_in[3];
    const float* iE   = (const float*)d_in[4];
    float*       acc  = (float*)d_out;

    const size_t nd      = (size_t)N_NODE * DIM;     // 19.2M floats
    const size_t ndBytes = nd * sizeof(float);       // 76.8 MB

    char* base = (char*)d_ws;
    float* bufA = (float*)(base);
    float* bufB = (float*)(base + ndBytes);

    const int n4      = (int)(nd / 4);
    const int cpyBlks = (n4 + 255) / 256;

    // Workspace layout. tmp/rowlow (build-time only) alias bufA/bufB:
    // build runs first, concat_init overwrites bufA afterwards.
    int2*          tmp    = (int2*)base;                          // 80 MB
    unsigned char* rowlow = (unsigned char*)(base + (size_t)N_EDGE * 8); // 10 MB
    size_t off = 2 * ndBytes;                                     // 153.6 MB
    int2* pairs = (int2*)(base + off);  off += (size_t)N_EDGE * sizeof(int2); // 80 MB
    int* rowPtr = (int*)(base + off);   off += (size_t)(N_NODE + 1) * sizeof(int);
    off = (off + 15) & ~(size_t)15;
    int* bucketCnt = (int*)(base + off); off += (size_t)NB * sizeof(int);
    int* bucketPtr = (int*)(base + off); off += (size_t)(NB + 1) * sizeof(int);
    int* cursorB   = (int*)(base + off); off += (size_t)NB * sizeof(int);
    const bool useCSR = (ws_size >= off);

    if (useCSR) {
        // ---- Build CSR (bucketed two-pass counting sort) ----
        hipMemsetAsync(bucketCnt, 0, (size_t)NB * sizeof(int), stream);
        hist_buckets<<<1024, 256, 0, stream>>>(rows, bucketCnt);
        bucket_scan<<<1, 256, 0, stream>>>(bucketCnt, bucketPtr, cursorB);
        const int e4Blks = (N_EDGE / 4 + 255) / 256;
        bucket_scatter<<<e4Blks, 256, 0, stream>>>(rows, cols, vals, cursorB,
                                                   tmp, rowlow);
        build_csr_bucket<<<NB, 256, 0, stream>>>(bucketPtr, tmp, rowlow,
                                                 rowPtr, pairs);

        // ---- Embeddings + 3 propagation layers ----
        concat_init<<<cpyBlks, 256, 0, stream>>>(uE, iE, bufA, acc);
        const int spmmBlks = (int)(((size_t)N_NODE * 64 + 255) / 256);
        float* cur = bufA;
        float* nxt = bufB;
        for (int l = 0; l < N_LAYER; ++l) {
            spmm_csr<<<spmmBlks, 256, 0, stream>>>(rowPtr, pairs, cur, nxt, acc);
            float* t = cur; cur = nxt; nxt = t;
        }
    } else {
        // Fallback: atomic scatter path
        concat_init<<<cpyBlks, 256, 0, stream>>>(uE, iE, bufA, acc);
        const int waves    = (N_EDGE + 63) / 64;
        const int spmmBlks = (int)(((long long)waves * 64 + 255) / 256);
        float* cur = bufA;
        float* nxt = bufB;
        for (int l = 0; l < N_LAYER; ++l) {
            hipMemsetAsync(nxt, 0, ndBytes, stream);
            spmm_atomic<<<spmmBlks, 256, 0, stream>>>(rows, cols, vals, cur, nxt);
            acc_add<<<cpyBlks, 256, 0, stream>>>(nxt, acc);
            float* t = cur; cur = nxt; nxt = t;
        }
    }
}

// Round 4
// 1546.664 us; speedup vs baseline: 1.6127x; 1.6127x over previous
//
#include <hip/hip_runtime.h>
#include <stdint.h>

// Problem constants (from reference)
#define N_USER 100000
#define N_ITEM 200000
#define N_NODE 300000   // N_USER + N_ITEM
#define DIM    64
#define N_EDGE 10000000
#define N_LAYER 3

// Radix-partition parameters
#define BROWS 1024                              // rows per bucket (row >> 10)
#define NB ((N_NODE + BROWS - 1) / BROWS)       // 293 buckets
#define G_PART 512                              // partition grid blocks
#define CHUNK ((N_EDGE + G_PART - 1) / G_PART)  // 19532 (divisible by 4)
#define COL_BITS 19                             // col < 300000 < 2^19
#define COL_MASK ((1 << COL_BITS) - 1)

// ---------------------------------------------------------------------------
// concat(u, i) -> cur  and  acc (= layer-0 term of the output sum)
// ---------------------------------------------------------------------------
__global__ __launch_bounds__(256) void concat_init(
    const float* __restrict__ uE, const float* __restrict__ iE,
    float* __restrict__ cur, float* __restrict__ acc)
{
    int i = blockIdx.x * blockDim.x + threadIdx.x;    // float4 index
    const int n4 = N_NODE * DIM / 4;
    if (i >= n4) return;
    int off = i * 4;
    const int ubound = N_USER * DIM;
    const float* src = (off < ubound) ? (uE + off) : (iE + (off - ubound));
    float4 x = *(const float4*)src;
    *(float4*)(cur + off) = x;
    *(float4*)(acc + off) = x;
}

// ---------------------------------------------------------------------------
// Step 1: per-block bucket histogram (LDS privatized, no global atomics).
// histT[bucket * G_PART + blk] = count of edges in blk's chunk with that bucket
// ---------------------------------------------------------------------------
__global__ __launch_bounds__(256) void hist_pass(
    const int* __restrict__ rows, int* __restrict__ histT)
{
    __shared__ int h[NB];
    for (int i = threadIdx.x; i < NB; i += 256) h[i] = 0;
    __syncthreads();
    const int blk = blockIdx.x;
    const int s = blk * CHUNK;
    const int e = min(s + CHUNK, N_EDGE);
    for (int i4 = s / 4 + threadIdx.x; i4 < e / 4; i4 += 256) {
        int4 r = ((const int4*)rows)[i4];
        atomicAdd(&h[r.x >> 10], 1);
        atomicAdd(&h[r.y >> 10], 1);
        atomicAdd(&h[r.z >> 10], 1);
        atomicAdd(&h[r.w >> 10], 1);
    }
    __syncthreads();
    for (int i = threadIdx.x; i < NB; i += 256)
        histT[i * G_PART + blk] = h[i];
}

// ---------------------------------------------------------------------------
// Step 2a: per-bucket exclusive scan over the G_PART block counts.
// offs[bucket][blk] = exclusive prefix within bucket; totals[bucket] = sum.
// ---------------------------------------------------------------------------
__global__ __launch_bounds__(G_PART) void bucket_scan1(
    const int* __restrict__ histT, int* __restrict__ offs,
    int* __restrict__ totals)
{
    __shared__ int s[G_PART];
    const int b = blockIdx.x;
    int x = histT[b * G_PART + threadIdx.x];
    s[threadIdx.x] = x;
    __syncthreads();
    for (int off = 1; off < G_PART; off <<= 1) {
        int t = (threadIdx.x >= off) ? s[threadIdx.x - off] : 0;
        __syncthreads();
        s[threadIdx.x] += t;
        __syncthreads();
    }
    int incl = s[threadIdx.x];
    offs[b * G_PART + threadIdx.x] = incl - x;
    if (threadIdx.x == G_PART - 1) totals[b] = incl;
}

// ---------------------------------------------------------------------------
// Step 2b: exclusive scan over the NB bucket totals (NB=293 <= 512, one pass)
// ---------------------------------------------------------------------------
__global__ __launch_bounds__(512) void base_scan(
    const int* __restrict__ totals, int* __restrict__ bucketBase,
    int* __restrict__ bucketPtr)
{
    __shared__ int s[512];
    int x = (threadIdx.x < NB) ? totals[threadIdx.x] : 0;
    s[threadIdx.x] = x;
    __syncthreads();
    for (int off = 1; off < 512; off <<= 1) {
        int t = (threadIdx.x >= off) ? s[threadIdx.x - off] : 0;
        __syncthreads();
        s[threadIdx.x] += t;
        __syncthreads();
    }
    int excl = s[threadIdx.x] - x;
    if (threadIdx.x < NB) {
        bucketBase[threadIdx.x] = excl;
        bucketPtr[threadIdx.x]  = excl;
    }
    if (threadIdx.x == 0) bucketPtr[NB] = N_EDGE;
}

// ---------------------------------------------------------------------------
// Step 3: partition. Each block writes its edges into its OWN contiguous
// per-(block,bucket) segments -> single-writer lines, full L2 line assembly.
// tmp entry: ((row & 1023) << 19) | col  packed with val.
// ---------------------------------------------------------------------------
__global__ __launch_bounds__(256) void partition_pass(
    const int* __restrict__ rows, const int* __restrict__ cols,
    const float* __restrict__ vals, const int* __restrict__ offs,
    const int* __restrict__ bucketBase, int2* __restrict__ tmp)
{
    __shared__ int cur[NB];
    const int blk = blockIdx.x;
    for (int i = threadIdx.x; i < NB; i += 256)
        cur[i] = offs[i * G_PART + blk] + bucketBase[i];
    __syncthreads();
    const int s = blk * CHUNK;
    const int e = min(s + CHUNK, N_EDGE);
    for (int i4 = s / 4 + threadIdx.x; i4 < e / 4; i4 += 256) {
        int4   r = ((const int4*)rows)[i4];
        int4   c = ((const int4*)cols)[i4];
        float4 v = ((const float4*)vals)[i4];

        int pos = atomicAdd(&cur[r.x >> 10], 1);
        tmp[pos] = make_int2(((r.x & 1023) << COL_BITS) | c.x, __float_as_int(v.x));
        pos = atomicAdd(&cur[r.y >> 10], 1);
        tmp[pos] = make_int2(((r.y & 1023) << COL_BITS) | c.y, __float_as_int(v.y));
        pos = atomicAdd(&cur[r.z >> 10], 1);
        tmp[pos] = make_int2(((r.z & 1023) << COL_BITS) | c.z, __float_as_int(v.z));
        pos = atomicAdd(&cur[r.w >> 10], 1);
        tmp[pos] = make_int2(((r.w & 1023) << COL_BITS) | c.w, __float_as_int(v.w));
    }
}

// ---------------------------------------------------------------------------
// Step 4: per-bucket counting sort -> final CSR (rowPtr + (col,val) pairs).
// One block per bucket; all writes inside the bucket's single-writer window.
// ---------------------------------------------------------------------------
__global__ __launch_bounds__(1024) void build_csr(
    const int* __restrict__ bucketPtr, const int2* __restrict__ tmp,
    int* __restrict__ rowPtr, int2* __restrict__ pairs)
{
    __shared__ int h[BROWS];
    __shared__ int sc[BROWS];
    const int b   = blockIdx.x;
    const int bs  = bucketPtr[b];
    const int be  = bucketPtr[b + 1];
    const int n   = be - bs;
    const int tid = threadIdx.x;

    h[tid] = 0;
    __syncthreads();
    for (int i = tid; i < n; i += 1024)
        atomicAdd(&h[tmp[bs + i].x >> COL_BITS], 1);
    __syncthreads();
    sc[tid] = h[tid];
    __syncthreads();
    for (int off = 1; off < BROWS; off <<= 1) {
        int t = (tid >= off) ? sc[tid - off] : 0;
        __syncthreads();
        sc[tid] += t;
        __syncthreads();
    }
    int excl = sc[tid] - h[tid];
    int row  = b * BROWS + tid;
    if (row < N_NODE) rowPtr[row] = bs + excl;
    if (b == 0 && tid == 0) rowPtr[N_NODE] = N_EDGE;
    h[tid] = excl;                   // reuse as local cursor
    __syncthreads();
    for (int i = tid; i < n; i += 1024) {
        int2 p = tmp[bs + i];
        int  r = p.x >> COL_BITS;
        int  pos = bs + atomicAdd(&h[r], 1);
        pairs[pos] = make_int2(p.x & COL_MASK, p.y);
    }
}

// ---------------------------------------------------------------------------
// CSR SpMM, no atomics. One wave per row; lane = dim element. acc += fused.
// ---------------------------------------------------------------------------
__global__ __launch_bounds__(256) void spmm_csr(
    const int*  __restrict__ rowPtr,
    const int2* __restrict__ pairs,
    const float* __restrict__ cur,
    float* __restrict__ nxt,
    float* __restrict__ acc)
{
    const int wid  = (blockIdx.x * blockDim.x + threadIdx.x) >> 6;  // row
    const int lane = threadIdx.x & 63;
    if (wid >= N_NODE) return;

    const int start = rowPtr[wid];
    const int end   = rowPtr[wid + 1];

    float sum = 0.0f;
    for (int e0 = start; e0 < end; e0 += 64) {
        const int n = min(64, end - e0);
        int   c = 0;
        float v = 0.0f;
        if (lane < n) {
            int2 p = pairs[e0 + lane];
            c = p.x;
            v = __int_as_float(p.y);
        }
        int j = 0;
        for (; j + 4 <= n; j += 4) {
            int   c0 = __shfl(c, j);     float v0 = __shfl(v, j);
            int   c1 = __shfl(c, j + 1); float v1 = __shfl(v, j + 1);
            int   c2 = __shfl(c, j + 2); float v2 = __shfl(v, j + 2);
            int   c3 = __shfl(c, j + 3); float v3 = __shfl(v, j + 3);
            float x0 = cur[c0 * DIM + lane];
            float x1 = cur[c1 * DIM + lane];
            float x2 = cur[c2 * DIM + lane];
            float x3 = cur[c3 * DIM + lane];
            sum += v0 * x0;
            sum += v1 * x1;
            sum += v2 * x2;
            sum += v3 * x3;
        }
        for (; j < n; ++j) {
            int   cc = __shfl(c, j);
            float vv = __shfl(v, j);
            sum += vv * cur[cc * DIM + lane];
        }
    }
    const int idx = wid * DIM + lane;
    nxt[idx] = sum;
    acc[idx] += sum;
}

// ---------------------------------------------------------------------------
// Fallback path (atomic scatter) if ws_size is too small for CSR buffers
// ---------------------------------------------------------------------------
__global__ __launch_bounds__(256) void spmm_atomic(
    const int*   __restrict__ rows,
    const int*   __restrict__ cols,
    const float* __restrict__ vals,
    const float* __restrict__ cur,
    float*       __restrict__ next)
{
    const int lane = threadIdx.x & 63;
    const int wave = (blockIdx.x * blockDim.x + threadIdx.x) >> 6;
    const int base = wave * 64;
    if (base >= N_EDGE) return;

    int   r64 = 0, c64 = 0;
    float v64 = 0.0f;
    const int e = base + lane;
    if (e < N_EDGE) { r64 = rows[e]; c64 = cols[e]; v64 = vals[e]; }
    const int nloc = min(64, N_EDGE - base);
    const int sub = lane >> 4;
    const int d4  = (lane & 15) << 2;

    #pragma unroll 4
    for (int j = 0; j < 64; j += 4) {
        const int   eidx = j + sub;
        const int   r = __shfl(r64, eidx);
        const int   c = __shfl(c64, eidx);
        const float v = __shfl(v64, eidx);
        if (eidx < nloc) {
            const float4 x = *(const float4*)(cur + c * DIM + d4);
            float* dst = next + r * DIM + d4;
            unsafeAtomicAdd(dst + 0, v * x.x);
            unsafeAtomicAdd(dst + 1, v * x.y);
            unsafeAtomicAdd(dst + 2, v * x.z);
            unsafeAtomicAdd(dst + 3, v * x.w);
        }
    }
}

__global__ __launch_bounds__(256) void acc_add(
    const float* __restrict__ next, float* __restrict__ acc)
{
    int i = blockIdx.x * blockDim.x + threadIdx.x;
    const int n4 = N_NODE * DIM / 4;
    if (i >= n4) return;
    int off = i * 4;
    float4 a = *(float4*)(acc + off);
    float4 b = *(const float4*)(next + off);
    a.x += b.x; a.y += b.y; a.z += b.z; a.w += b.w;
    *(float4*)(acc + off) = a;
}

extern "C" void kernel_launch(void* const* d_in, const int* in_sizes, int n_in,
                              void* d_out, int out_size, void* d_ws, size_t ws_size,
                              hipStream_t stream)
{
    const int*   rows = (const int*)  d_in[0];
    const int*   cols = (const int*)  d_in[1];
    const float* vals = (const float*)d_in[2];
    const float* uE   = (const float*)d_in[3];
    const float* iE   = (const float*)d_in[4];
    float*       acc  = (float*)d_out;

    const size_t nd      = (size_t)N_NODE * DIM;     // 19.2M floats
    const size_t ndBytes = nd * sizeof(float);       // 76.8 MB

    char* base = (char*)d_ws;
    float* bufA = (float*)(base);
    float* bufB = (float*)(base + ndBytes);

    const int n4      = (int)(nd / 4);
    const int cpyBlks = (n4 + 255) / 256;

    // Workspace layout. tmp (build-time only, 80 MB) aliases bufA/bufB head:
    // the build runs before concat_init overwrites bufA.
    int2* tmp = (int2*)base;
    size_t off = 2 * ndBytes;                                     // 153.6 MB
    int2* pairs = (int2*)(base + off);  off += (size_t)N_EDGE * sizeof(int2); // 80 MB
    int* rowPtr = (int*)(base + off);   off += (size_t)(N_NODE + 1) * sizeof(int);
    off = (off + 15) & ~(size_t)15;
    int* histT      = (int*)(base + off); off += (size_t)NB * G_PART * sizeof(int);
    int* offs       = (int*)(base + off); off += (size_t)NB * G_PART * sizeof(int);
    int* totals     = (int*)(base + off); off += (size_t)NB * sizeof(int);
    int* bucketBase = (int*)(base + off); off += (size_t)NB * sizeof(int);
    int* bucketPtr  = (int*)(base + off); off += (size_t)(NB + 1) * sizeof(int);
    const bool useCSR = (ws_size >= off);

    if (useCSR) {
        // ---- Build CSR (deterministic radix partition + per-bucket sort) ----
        hist_pass<<<G_PART, 256, 0, stream>>>(rows, histT);
        bucket_scan1<<<NB, G_PART, 0, stream>>>(histT, offs, totals);
        base_scan<<<1, 512, 0, stream>>>(totals, bucketBase, bucketPtr);
        partition_pass<<<G_PART, 256, 0, stream>>>(rows, cols, vals, offs,
                                                   bucketBase, tmp);
        build_csr<<<NB, 1024, 0, stream>>>(bucketPtr, tmp, rowPtr, pairs);

        // ---- Embeddings + 3 propagation layers ----
        concat_init<<<cpyBlks, 256, 0, stream>>>(uE, iE, bufA, acc);
        const int spmmBlks = (int)(((size_t)N_NODE * 64 + 255) / 256);
        float* cur = bufA;
        float* nxt = bufB;
        for (int l = 0; l < N_LAYER; ++l) {
            spmm_csr<<<spmmBlks, 256, 0, stream>>>(rowPtr, pairs, cur, nxt, acc);
            float* t = cur; cur = nxt; nxt = t;
        }
    } else {
        // Fallback: atomic scatter path
        concat_init<<<cpyBlks, 256, 0, stream>>>(uE, iE, bufA, acc);
        const int waves    = (N_EDGE + 63) / 64;
        const int spmmBlks = (int)(((long long)waves * 64 + 255) / 256);
        float* cur = bufA;
        float* nxt = bufB;
        for (int l = 0; l < N_LAYER; ++l) {
            hipMemsetAsync(nxt, 0, ndBytes, stream);
            spmm_atomic<<<spmmBlks, 256, 0, stream>>>(rows, cols, vals, cur, nxt);
            acc_add<<<cpyBlks, 256, 0, stream>>>(nxt, acc);
            float* t = cur; cur = nxt; nxt = t;
        }
    }
}